// Round 1
// baseline (338.952 us; speedup 1.0000x reference)
//
#include <hip/hip_runtime.h>
#include <hip/hip_bf16.h>

#define BATCH 262144
#define DIN 48
#define HDIM 256
#define DOUT 12
#define BM 64
#define NBLOCKS (BATCH / BM)
#define EPSV 1e-5f

typedef __attribute__((ext_vector_type(4))) float f32x4;
typedef __attribute__((ext_vector_type(8))) short bf16x8;

// ws layout in ushort elements
#define W1T_OFF 0          // [256][64]   (K padded 48->64 with zeros)
#define W2T_OFF 16384      // [256][256]
#define W3T_OFF 81920      // [256][256]
#define WMT_OFF 147456     // [16][256]   (N padded 12->16 with zeros)
#define WS_ELEMS 151552

__device__ __forceinline__ unsigned short f2b(float f) {
    union { float f; unsigned u; } v; v.f = f;
    unsigned r = (v.u + 0x7fffu + ((v.u >> 16) & 1u)) >> 16;  // round-nearest-even
    return (unsigned short)r;
}

__global__ void conv_w_kernel(const float* __restrict__ W1, const float* __restrict__ W2,
                              const float* __restrict__ W3, const float* __restrict__ Wm,
                              unsigned short* __restrict__ ws) {
    int i = blockIdx.x * 256 + threadIdx.x;
    if (i >= WS_ELEMS) return;
    float v;
    if (i < W2T_OFF) {                 // W1^T [n<256][k<64]
        int n = i >> 6, k = i & 63;
        v = (k < DIN) ? W1[k * HDIM + n] : 0.0f;
    } else if (i < W3T_OFF) {          // W2^T [n][k]
        int j = i - W2T_OFF; int n = j >> 8, k = j & 255;
        v = W2[k * HDIM + n];
    } else if (i < WMT_OFF) {          // W3^T [n][k]
        int j = i - W3T_OFF; int n = j >> 8, k = j & 255;
        v = W3[k * HDIM + n];
    } else {                           // Wm^T [n<16][k<256]
        int j = i - WMT_OFF; int n = j >> 8, k = j & 255;
        v = (n < DOUT) ? Wm[k * DOUT + n] : 0.0f;
    }
    ws[i] = f2b(v);
}

// LDS swizzle: XOR byte-bits 4..6 with (row&7) -> ushort index XOR ((row&7)<<3).
// Bijective within each 64-col block; keeps 16B-aligned 8-ushort groups contiguous.
__device__ __forceinline__ int swz(int row, int col) {
    return row * 256 + (col ^ ((row & 7) << 3));
}

// One Linear(K->256) + LayerNorm + ReLU layer. src/dst are [64][256] bf16 LDS (swizzled).
template<int K>
__device__ __forceinline__ void layer_mm(
    const unsigned short* __restrict__ wt,   // W^T bf16 [256][K]
    const float* __restrict__ bias, const float* __restrict__ gg, const float* __restrict__ bb,
    const unsigned short* src, unsigned short* dst,
    float (*red)[64][2], float* mu_s, float* rs_s)
{
    const int tid = threadIdx.x;
    const int wv = tid >> 6, lane = tid & 63, l15 = lane & 15, l4 = lane >> 4;
    const int nbase = wv * 32;

    f32x4 acc[4][2] = {};
    #pragma unroll 2
    for (int kk = 0; kk < K; kk += 32) {
        const int k0 = kk + l4 * 8;
        bf16x8 a[4], b[2];
        #pragma unroll
        for (int n = 0; n < 2; n++)
            b[n] = *(const bf16x8*)&wt[(nbase + n * 16 + l15) * K + k0];
        #pragma unroll
        for (int m = 0; m < 4; m++)
            a[m] = *(const bf16x8*)&src[swz(m * 16 + l15, k0)];
        #pragma unroll
        for (int m = 0; m < 4; m++)
            #pragma unroll
            for (int n = 0; n < 2; n++)
                acc[m][n] = __builtin_amdgcn_mfma_f32_16x16x32_bf16(a[m], b[n], acc[m][n], 0, 0, 0);
    }

    // bias + per-row (sum, sumsq) partials over this wave's 32 cols
    const int c0 = nbase + l15, c1 = c0 + 16;
    const float bias0 = bias[c0], bias1 = bias[c1];
    #pragma unroll
    for (int m = 0; m < 4; m++) {
        #pragma unroll
        for (int j = 0; j < 4; j++) {
            float a0 = acc[m][0][j] + bias0;
            float a1 = acc[m][1][j] + bias1;
            acc[m][0][j] = a0; acc[m][1][j] = a1;
            float ss = a0 + a1;
            float qq = a0 * a0 + a1 * a1;
            ss += __shfl_xor(ss, 1); qq += __shfl_xor(qq, 1);
            ss += __shfl_xor(ss, 2); qq += __shfl_xor(qq, 2);
            ss += __shfl_xor(ss, 4); qq += __shfl_xor(qq, 4);
            ss += __shfl_xor(ss, 8); qq += __shfl_xor(qq, 8);
            if (l15 == 0) {
                const int row = m * 16 + l4 * 4 + j;
                red[wv][row][0] = ss;
                red[wv][row][1] = qq;
            }
        }
    }
    __syncthreads();

    if (tid < 64) {
        float S = 0.f, Q = 0.f;
        #pragma unroll
        for (int w = 0; w < 8; w++) { S += red[w][tid][0]; Q += red[w][tid][1]; }
        const float mu = S * (1.0f / 256.0f);
        const float var = Q * (1.0f / 256.0f) - mu * mu;
        mu_s[tid] = mu;
        rs_s[tid] = rsqrtf(var + EPSV);
    }
    __syncthreads();

    const float g0 = gg[c0], g1 = gg[c1], be0 = bb[c0], be1 = bb[c1];
    #pragma unroll
    for (int m = 0; m < 4; m++) {
        #pragma unroll
        for (int j = 0; j < 4; j++) {
            const int row = m * 16 + l4 * 4 + j;
            const float mu = mu_s[row], rs = rs_s[row];
            const float h0 = fmaxf(fmaf((acc[m][0][j] - mu) * rs, g0, be0), 0.0f);
            const float h1 = fmaxf(fmaf((acc[m][1][j] - mu) * rs, g1, be1), 0.0f);
            dst[swz(row, c0)] = f2b(h0);
            dst[swz(row, c1)] = f2b(h1);
        }
    }
    __syncthreads();
}

__global__ __launch_bounds__(512, 4) void fused_mlp(
    const float* __restrict__ x,
    const float* __restrict__ b1, const float* __restrict__ g1, const float* __restrict__ be1,
    const float* __restrict__ b2, const float* __restrict__ g2, const float* __restrict__ be2,
    const float* __restrict__ b3, const float* __restrict__ g3, const float* __restrict__ be3,
    const float* __restrict__ bm,
    const unsigned short* __restrict__ ws,
    float* __restrict__ out)
{
    __shared__ unsigned short bufA[BM * 256];
    __shared__ unsigned short bufB[BM * 256];
    __shared__ float red[8][64][2];
    __shared__ float mu_s[64], rs_s[64];

    const int tid = threadIdx.x;
    const int row0 = blockIdx.x * BM;

    // phase 0: stage x tile -> bufA as bf16, K padded 48->64 with zeros
    {
        const int r = tid >> 3;         // 0..63
        const int c0 = (tid & 7) * 6;   // 0,6,...,42
        const float* xr = x + (size_t)(row0 + r) * DIN + c0;
        #pragma unroll
        for (int i = 0; i < 6; i++)
            bufA[swz(r, c0 + i)] = f2b(xr[i]);
        const int zc = DIN + (tid & 7) * 2;   // 48..62
        bufA[swz(r, zc)] = 0;
        bufA[swz(r, zc + 1)] = 0;
    }
    __syncthreads();

    layer_mm<64>(ws + W1T_OFF, b1, g1, be1, bufA, bufB, red, mu_s, rs_s);
    layer_mm<256>(ws + W2T_OFF, b2, g2, be2, bufB, bufA, red, mu_s, rs_s);
    layer_mm<256>(ws + W3T_OFF, b3, g3, be3, bufA, bufB, red, mu_s, rs_s);

    // final layer: [64][256] @ WmT[16][256] -> tanh -> out[64][12], split-K over wave pairs
    {
        const int wv = tid >> 6, lane = tid & 63, l15 = lane & 15, l4 = lane >> 4;
        const int m = wv & 3, kh = wv >> 2;
        f32x4 acc = {0.f, 0.f, 0.f, 0.f};
        const unsigned short* wmt = ws + WMT_OFF;
        #pragma unroll
        for (int t = 0; t < 4; t++) {
            const int k0 = kh * 128 + t * 32 + l4 * 8;
            bf16x8 a = *(const bf16x8*)&bufB[swz(m * 16 + l15, k0)];
            bf16x8 b = *(const bf16x8*)&wmt[l15 * 256 + k0];
            acc = __builtin_amdgcn_mfma_f32_16x16x32_bf16(a, b, acc, 0, 0, 0);
        }
        float* part = (float*)red;    // 4*16*16 = 1024 floats, fits exactly
        if (kh == 1) {
            #pragma unroll
            for (int j = 0; j < 4; j++)
                part[m * 256 + (l4 * 4 + j) * 16 + l15] = acc[j];
        }
        __syncthreads();
        if (kh == 0 && l15 < DOUT) {
            const float bmv = bm[l15];
            #pragma unroll
            for (int j = 0; j < 4; j++) {
                const float z = acc[j] + part[m * 256 + (l4 * 4 + j) * 16 + l15] + bmv;
                const int row = row0 + m * 16 + l4 * 4 + j;
                out[(size_t)row * DOUT + l15] = tanhf(z);
            }
        }
    }
}

extern "C" void kernel_launch(void* const* d_in, const int* in_sizes, int n_in,
                              void* d_out, int out_size, void* d_ws, size_t ws_size,
                              hipStream_t stream)
{
    const float* x   = (const float*)d_in[0];
    const float* W1  = (const float*)d_in[1];
    const float* b1  = (const float*)d_in[2];
    const float* g1  = (const float*)d_in[3];
    const float* be1 = (const float*)d_in[4];
    const float* W2  = (const float*)d_in[5];
    const float* b2  = (const float*)d_in[6];
    const float* g2  = (const float*)d_in[7];
    const float* be2 = (const float*)d_in[8];
    const float* W3  = (const float*)d_in[9];
    const float* b3  = (const float*)d_in[10];
    const float* g3  = (const float*)d_in[11];
    const float* be3 = (const float*)d_in[12];
    const float* Wm  = (const float*)d_in[13];
    const float* bm  = (const float*)d_in[14];
    unsigned short* ws = (unsigned short*)d_ws;
    float* out = (float*)d_out;

    conv_w_kernel<<<(WS_ELEMS + 255) / 256, 256, 0, stream>>>(W1, W2, W3, Wm, ws);
    fused_mlp<<<NBLOCKS, 512, 0, stream>>>(x, b1, g1, be1, b2, g2, be2,
                                           b3, g3, be3, bm, ws, out);
}

// Round 2
// 316.956 us; speedup vs baseline: 1.0694x; 1.0694x over previous
//
#include <hip/hip_runtime.h>
#include <hip/hip_bf16.h>

#define BATCH 262144
#define DIN 48
#define HDIM 256
#define DOUT 12
#define BM 128
#define NBLK (BATCH / BM)
#define EPSV 1e-5f

typedef __attribute__((ext_vector_type(4))) float f32x4;
typedef __attribute__((ext_vector_type(8))) short bf16x8;

// ws layout in ushort elements
#define W1T_OFF 0          // [256][64]   (K padded 48->64 with zeros)
#define W2T_OFF 16384      // [256][256]
#define W3T_OFF 81920      // [256][256]
#define WMT_OFF 147456     // [16][256]   (N padded 12->16 with zeros)
#define WS_ELEMS 151552

__device__ __forceinline__ unsigned short f2b(float f) {
    union { float f; unsigned u; } v; v.f = f;
    unsigned r = (v.u + 0x7fffu + ((v.u >> 16) & 1u)) >> 16;  // RNE
    return (unsigned short)r;
}

__global__ void conv_w_kernel(const float* __restrict__ W1, const float* __restrict__ W2,
                              const float* __restrict__ W3, const float* __restrict__ Wm,
                              unsigned short* __restrict__ ws) {
    int i = blockIdx.x * 256 + threadIdx.x;
    if (i >= WS_ELEMS) return;
    float v;
    if (i < W2T_OFF) {                 // W1^T [n<256][k<64]
        int n = i >> 6, k = i & 63;
        v = (k < DIN) ? W1[k * HDIM + n] : 0.0f;
    } else if (i < W3T_OFF) {          // W2^T [n][k]
        int j = i - W2T_OFF; int n = j >> 8, k = j & 255;
        v = W2[k * HDIM + n];
    } else if (i < WMT_OFF) {          // W3^T [n][k]
        int j = i - W3T_OFF; int n = j >> 8, k = j & 255;
        v = W3[k * HDIM + n];
    } else {                           // Wm^T [n<16][k<256]
        int j = i - WMT_OFF; int n = j >> 8, k = j & 255;
        v = (n < DOUT) ? Wm[k * DOUT + n] : 0.0f;
    }
    ws[i] = f2b(v);
}

// LDS swizzle: ushort index XOR ((row&7)<<3) == byte XOR ((row&7)<<4).
// Keeps 8B-aligned ushort4 / 16B bf16x8 groups contiguous (bits 0..2 untouched).
__device__ __forceinline__ int swz(int row, int col) {
    return row * 256 + (col ^ ((row & 7) << 3));
}

template<int K>
__device__ __forceinline__ void layer_mm(
    const unsigned short* __restrict__ wt,   // W^T bf16 [256][K]
    const float* __restrict__ bias, const float* __restrict__ gg, const float* __restrict__ bb,
    unsigned short* buf, float (*red)[BM][2], float (*murs)[2])
{
    const int tid = threadIdx.x;
    const int wv = tid >> 6, lane = tid & 63, l15 = lane & 15, l4 = lane >> 4;
    const int n0 = wv * 64;

    float bia[4];
    #pragma unroll
    for (int n = 0; n < 4; n++) bia[n] = bias[n0 + n * 16 + l15];

    f32x4 acc[8][4] = {};
    #pragma unroll 2
    for (int kk = 0; kk < K; kk += 32) {
        const int k0 = kk + l4 * 8;
        bf16x8 b[4], a[8];
        #pragma unroll
        for (int n = 0; n < 4; n++)
            b[n] = *(const bf16x8*)&wt[(n0 + n * 16 + l15) * K + k0];
        #pragma unroll
        for (int m = 0; m < 8; m++)
            a[m] = *(const bf16x8*)&buf[swz(m * 16 + l15, k0)];
        #pragma unroll
        for (int m = 0; m < 8; m++)
            #pragma unroll
            for (int n = 0; n < 4; n++)
                acc[m][n] = __builtin_amdgcn_mfma_f32_16x16x32_bf16(a[m], b[n], acc[m][n], 0, 0, 0);
    }

    // bias + per-row (sum, sumsq) partials over this wave's 64 cols
    #pragma unroll
    for (int m = 0; m < 8; m++) {
        #pragma unroll
        for (int j = 0; j < 4; j++) {
            float ss = 0.f, qq = 0.f;
            #pragma unroll
            for (int n = 0; n < 4; n++) {
                float v = acc[m][n][j] + bia[n];
                acc[m][n][j] = v;
                ss += v;
                qq = fmaf(v, v, qq);
            }
            ss += __shfl_xor(ss, 1); qq += __shfl_xor(qq, 1);
            ss += __shfl_xor(ss, 2); qq += __shfl_xor(qq, 2);
            ss += __shfl_xor(ss, 4); qq += __shfl_xor(qq, 4);
            ss += __shfl_xor(ss, 8); qq += __shfl_xor(qq, 8);
            if (l15 == 0) {
                float2* p = (float2*)&red[wv][m * 16 + l4 * 4 + j][0];
                *p = make_float2(ss, qq);
            }
        }
    }
    __syncthreads();   // also guarantees all k-loop reads of buf are drained

    if (tid < BM) {
        float S = 0.f, Q = 0.f;
        #pragma unroll
        for (int w = 0; w < 4; w++) { S += red[w][tid][0]; Q += red[w][tid][1]; }
        const float mu = S * (1.0f / 256.0f);
        const float var = Q * (1.0f / 256.0f) - mu * mu;
        murs[tid][0] = mu;
        murs[tid][1] = rsqrtf(var + EPSV);
    }
    __syncthreads();

    float g[4], be[4];
    #pragma unroll
    for (int n = 0; n < 4; n++) { g[n] = gg[n0 + n * 16 + l15]; be[n] = bb[n0 + n * 16 + l15]; }

    #pragma unroll
    for (int m = 0; m < 8; m++) {
        #pragma unroll
        for (int j = 0; j < 4; j++) {
            const int row = m * 16 + l4 * 4 + j;
            const float mu = murs[row][0], rs = murs[row][1];  // broadcast reads
            #pragma unroll
            for (int n = 0; n < 4; n++) {
                const float h = fmaxf(fmaf((acc[m][n][j] - mu) * rs, g[n], be[n]), 0.0f);
                buf[swz(row, n0 + n * 16 + l15)] = f2b(h);  // in-place: safe post-barrier
            }
        }
    }
    __syncthreads();
}

__global__ __launch_bounds__(256, 2) void fused_mlp(
    const float* __restrict__ x,
    const float* __restrict__ b1, const float* __restrict__ g1, const float* __restrict__ be1,
    const float* __restrict__ b2, const float* __restrict__ g2, const float* __restrict__ be2,
    const float* __restrict__ b3, const float* __restrict__ g3, const float* __restrict__ be3,
    const float* __restrict__ bm,
    const unsigned short* __restrict__ ws,
    float* __restrict__ out)
{
    __shared__ __align__(16) unsigned short buf[BM * 256];   // 64 KB, swizzled bf16
    __shared__ float red[4][BM][2];                          // 4 KB
    __shared__ float murs[BM][2];                            // 1 KB

    const int tid = threadIdx.x;
    const int wv = tid >> 6, lane = tid & 63, l15 = lane & 15, l4 = lane >> 4;
    const size_t row0 = (size_t)blockIdx.x * BM;

    // ---- stage x tile -> buf as bf16 (coalesced float4 reads), pad K 48->64 ----
    {
        const float4* xs = (const float4*)(x + row0 * DIN);
        #pragma unroll
        for (int q = 0; q < 6; q++) {
            const int i = tid + q * 256;           // i < 1536
            const float4 f = xs[i];
            const int flat = i * 4;
            const int r = flat / 48, c = flat % 48;
            ushort4 u = { f2b(f.x), f2b(f.y), f2b(f.z), f2b(f.w) };
            *(ushort4*)&buf[swz(r, c)] = u;
        }
        const int r = tid >> 1, c = DIN + (tid & 1) * 8;
        ushort4 z4 = {0, 0, 0, 0};
        *(ushort4*)&buf[swz(r, c)] = z4;
        *(ushort4*)&buf[swz(r, c + 4)] = z4;
    }
    __syncthreads();

    layer_mm<64>(ws + W1T_OFF, b1, g1, be1, buf, red, murs);
    layer_mm<256>(ws + W2T_OFF, b2, g2, be2, buf, red, murs);
    layer_mm<256>(ws + W3T_OFF, b3, g3, be3, buf, red, murs);

    // ---- final layer: split-K over the 4 waves, LDS reduce, coalesced store ----
    {
        const unsigned short* wmt = ws + WMT_OFF;
        f32x4 facc[8] = {};
        #pragma unroll
        for (int t = 0; t < 2; t++) {
            const int k0 = wv * 64 + t * 32 + l4 * 8;
            const bf16x8 b = *(const bf16x8*)&wmt[l15 * 256 + k0];
            #pragma unroll
            for (int m = 0; m < 8; m++) {
                const bf16x8 a = *(const bf16x8*)&buf[swz(m * 16 + l15, k0)];
                facc[m] = __builtin_amdgcn_mfma_f32_16x16x32_bf16(a, b, facc[m], 0, 0, 0);
            }
        }
        __syncthreads();   // all reads of buf complete before overwrite

        float* part = (float*)buf;            // [4][8][16][17] padded, 34.8 KB
        #pragma unroll
        for (int m = 0; m < 8; m++)
            #pragma unroll
            for (int j = 0; j < 4; j++)
                part[((wv * 8 + m) * 16 + l4 * 4 + j) * 17 + l15] = facc[m][j];
        __syncthreads();

        float* ost = (float*)buf + 8704;      // [BM][12] f32 out stage, 6 KB
        const float bmv = bm[l15 < DOUT ? l15 : 0];
        #pragma unroll
        for (int q = 0; q < 2; q++) {
            const int mm = wv * 2 + q;
            #pragma unroll
            for (int j = 0; j < 4; j++) {
                const int rr = l4 * 4 + j;
                float s = 0.f;
                #pragma unroll
                for (int w = 0; w < 4; w++)
                    s += part[((w * 8 + mm) * 16 + rr) * 17 + l15];
                const float o = tanhf(s + bmv);
                if (l15 < DOUT) ost[(mm * 16 + rr) * DOUT + l15] = o;
            }
        }
        __syncthreads();

        float4* og = (float4*)(out + row0 * DOUT);
        const float4* osv = (const float4*)ost;
        for (int i = tid; i < (BM * DOUT) / 4; i += 256)   // 384 float4 = 6 KB
            og[i] = osv[i];
    }
}

extern "C" void kernel_launch(void* const* d_in, const int* in_sizes, int n_in,
                              void* d_out, int out_size, void* d_ws, size_t ws_size,
                              hipStream_t stream)
{
    const float* x   = (const float*)d_in[0];
    const float* W1  = (const float*)d_in[1];
    const float* b1  = (const float*)d_in[2];
    const float* g1  = (const float*)d_in[3];
    const float* be1 = (const float*)d_in[4];
    const float* W2  = (const float*)d_in[5];
    const float* b2  = (const float*)d_in[6];
    const float* g2  = (const float*)d_in[7];
    const float* be2 = (const float*)d_in[8];
    const float* W3  = (const float*)d_in[9];
    const float* b3  = (const float*)d_in[10];
    const float* g3  = (const float*)d_in[11];
    const float* be3 = (const float*)d_in[12];
    const float* Wm  = (const float*)d_in[13];
    const float* bm  = (const float*)d_in[14];
    unsigned short* ws = (unsigned short*)d_ws;
    float* out = (float*)d_out;

    conv_w_kernel<<<(WS_ELEMS + 255) / 256, 256, 0, stream>>>(W1, W2, W3, Wm, ws);
    fused_mlp<<<NBLK, 256, 0, stream>>>(x, b1, g1, be1, b2, g2, be2,
                                        b3, g3, be3, bm, ws, out);
}